// Round 1
// baseline (212.817 us; speedup 1.0000x reference)
//
#include <hip/hip_runtime.h>
#include <hip/hip_bf16.h>
#include <math.h>

#define BATCH 4
#define NQ 8192
#define KNB 8
#define K1 9            // keep 9 per partition: self filtered at merge
#define TILE 2048
#define IDXMASK 8191u
#define KEYMASK 0xFFFFE000u  // keep sign+exp+10 mantissa bits, low 13 bits hold index

// guarded sorted insert of a packed key into ascending nk[0..K1-1]
#define PROC(VX, VY, VZ, CIDX) { \
  float dx = qx - (VX); float dy = qy - (VY); float dz = qz - (VZ); \
  float d = dx*dx + dy*dy + dz*dz; \
  unsigned key = (__float_as_uint(d) & KEYMASK) | (unsigned)(CIDX); \
  if (key < nk[K1-1]) { \
    unsigned kk = key; \
    _Pragma("unroll") \
    for (int j = 0; j < K1; ++j) { \
      unsigned lo = min(kk, nk[j]); unsigned hi = max(kk, nk[j]); \
      nk[j] = lo; kk = hi; } \
  } }

__global__ __launch_bounds__(256) void knn_kernel(
    const float* __restrict__ pc, unsigned* __restrict__ wsK,
    int P, int candPerPart)
{
  __shared__ float sx[TILE], sy[TILE], sz[TILE];
  const int b = blockIdx.y;
  const int p = blockIdx.z;
  const int q = blockIdx.x * 256 + threadIdx.x;
  const float* __restrict__ px = pc + (size_t)b * 3 * NQ;
  const float* __restrict__ py = px + NQ;
  const float* __restrict__ pz = px + 2 * NQ;
  const float qx = px[q], qy = py[q], qz = pz[q];

  unsigned nk[K1];
#pragma unroll
  for (int j = 0; j < K1; ++j) nk[j] = 0xFFFFFFFFu;

  const int c0 = p * candPerPart;
  for (int t = 0; t < candPerPart; t += TILE) {
    __syncthreads();
    {
      const float4* gx = (const float4*)(px + c0 + t);
      const float4* gy = (const float4*)(py + c0 + t);
      const float4* gz = (const float4*)(pz + c0 + t);
      float4* lx = (float4*)sx; float4* ly = (float4*)sy; float4* lz = (float4*)sz;
      for (int i = threadIdx.x; i < TILE / 4; i += 256) {
        lx[i] = gx[i]; ly[i] = gy[i]; lz[i] = gz[i];
      }
    }
    __syncthreads();
    const float4* sx4 = (const float4*)sx;
    const float4* sy4 = (const float4*)sy;
    const float4* sz4 = (const float4*)sz;
#pragma unroll 4
    for (int i4 = 0; i4 < TILE / 4; ++i4) {
      float4 vx = sx4[i4], vy = sy4[i4], vz = sz4[i4];
      int cb = c0 + t + i4 * 4;
      PROC(vx.x, vy.x, vz.x, cb + 0);
      PROC(vx.y, vy.y, vz.y, cb + 1);
      PROC(vx.z, vy.z, vz.z, cb + 2);
      PROC(vx.w, vy.w, vz.w, cb + 3);
    }
  }
  size_t o = ((size_t)((b * NQ + q) * P + p)) * K1;
#pragma unroll
  for (int j = 0; j < K1; ++j) wsK[o + j] = nk[j];
}

__global__ __launch_bounds__(256) void loss_kernel(
    const float* __restrict__ pc, const float* __restrict__ pf,
    const unsigned* __restrict__ wsK, float* __restrict__ acc, int P)
{
  const int b = blockIdx.y;
  const int q = blockIdx.x * 256 + threadIdx.x;
  const float* __restrict__ px = pc + (size_t)b * 3 * NQ;
  const float* __restrict__ py = px + NQ;
  const float* __restrict__ pz = px + 2 * NQ;
  const float* __restrict__ fx = pf + (size_t)b * 3 * NQ;
  const float* __restrict__ fy = fx + NQ;
  const float* __restrict__ fz = fx + 2 * NQ;

  unsigned nk[KNB];
#pragma unroll
  for (int j = 0; j < KNB; ++j) nk[j] = 0xFFFFFFFFu;

  const size_t o = (size_t)((b * NQ + q) * P) * K1;
  const int total = P * K1;
  for (int m = 0; m < total; ++m) {
    unsigned key = wsK[o + m];
    if ((key & IDXMASK) == (unsigned)q) continue;  // drop self
    if (key < nk[KNB - 1]) {
      unsigned kk = key;
#pragma unroll
      for (int j = 0; j < KNB; ++j) {
        unsigned lo = min(kk, nk[j]); unsigned hi = max(kk, nk[j]);
        nk[j] = lo; kk = hi;
      }
    }
  }

  const float qx = px[q], qy = py[q], qz = pz[q];
  const float fqx = fx[q], fqy = fy[q], fqz = fz[q];
  float ssum = 0.f, sdsum = 0.f;
#pragma unroll
  for (int j = 0; j < KNB; ++j) {
    int i = (int)(nk[j] & IDXMASK);
    // recompute exact distance (key truncation never affects the values)
    float dx = qx - px[i], dy = qy - py[i], dz = qz - pz[i];
    float d = dx * dx + dy * dy + dz * dz;
    float e = expf(expf(-2.0f * d));  // exp(exp(-d/alpha)), alpha=0.5
    float gx = fx[i] - fqx, gy = fy[i] - fqy, gz = fz[i] - fqz;
    float diff = sqrtf(gx * gx + gy * gy + gz * gz);
    ssum += e; sdsum += e * diff;
  }

  // wave reduce (wave64)
  for (int off = 32; off > 0; off >>= 1) {
    ssum += __shfl_down(ssum, off);
    sdsum += __shfl_down(sdsum, off);
  }
  __shared__ float r[8];
  const int lane = threadIdx.x & 63, wid = threadIdx.x >> 6;
  if (lane == 0) { r[wid * 2] = ssum; r[wid * 2 + 1] = sdsum; }
  __syncthreads();
  if (threadIdx.x == 0) {
    float s0 = r[0] + r[2] + r[4] + r[6];
    float s1 = r[1] + r[3] + r[5] + r[7];
    atomicAdd(&acc[b * 2 + 0], s0);
    atomicAdd(&acc[b * 2 + 1], s1);
  }
}

__global__ void final_kernel(const float* __restrict__ acc, float* __restrict__ out)
{
  if (threadIdx.x == 0) {
    float s = 0.f;
    for (int b = 0; b < BATCH; ++b) s += acc[b * 2 + 1] / acc[b * 2];
    out[0] = s * (1.0f / BATCH);
  }
}

extern "C" void kernel_launch(void* const* d_in, const int* in_sizes, int n_in,
                              void* d_out, int out_size, void* d_ws, size_t ws_size,
                              hipStream_t stream) {
  const float* pc = (const float*)d_in[0];   // pc1:      (4,3,8192) f32
  const float* pf = (const float*)d_in[1];   // pred_flow:(4,3,8192) f32
  float* out = (float*)d_out;                // scalar f32
  float* acc = (float*)d_ws;                 // 8 floats: per-batch {sum_e, sum_e_diff}
  unsigned* wsK = (unsigned*)((char*)d_ws + 256);

  const size_t needP4 = 256 + (size_t)BATCH * NQ * 4 * K1 * sizeof(unsigned);
  const int P = (ws_size >= needP4) ? 4 : 1;
  const int cpp = NQ / P;

  hipMemsetAsync(d_ws, 0, 256, stream);  // zero accumulators

  dim3 g1(NQ / 256, BATCH, P);
  knn_kernel<<<g1, 256, 0, stream>>>(pc, wsK, P, cpp);

  dim3 g2(NQ / 256, BATCH);
  loss_kernel<<<g2, 256, 0, stream>>>(pc, pf, wsK, acc, P);

  final_kernel<<<1, 64, 0, stream>>>(acc, out);
}